// Round 7
// baseline (603.312 us; speedup 1.0000x reference)
//
#include <hip/hip_runtime.h>
#include <math.h>

#define N_NODES 50000
#define N_EDGES 800000
#define IN_DIM 64
#define H_HEADS 4
#define D_HEAD 16
#define NT_TYPES 2
#define ET_TYPES 2
#define HD 64
#define NB_SCAN ((N_NODES + 255) / 256)   // 196
#define M_COLS 320                         // 64 q + 2et*128 interleaved (katt,vmsg)
#define M_PER_T (64 * M_COLS)              // 20480 floats per type
#define PCH 50                             // proj: type-list entries per block
#define OCH 100                            // out: type-list entries per block
#define LOG2E 1.44269504088896f

__device__ __forceinline__ unsigned int f32_to_bf16(float f) {
  unsigned int u = __float_as_uint(f);
  return (u + 0x7FFFu + ((u >> 16) & 1u)) >> 16;   // RNE
}

// ---------------------------------------------------------------------------
// Fold kernel: M[t][i][col] such that  y[n] = x[n] @ M[ntype[n]]  yields
//   col 0..63            -> q[n][col]
//   col 64+cc, et=cc>>7, r=cc&127, c=r>>1, half=r&1
//                        -> half==0: katt[et][n][c] ; half==1: vmsg[et][n][c]
// ---------------------------------------------------------------------------
__global__ void fold_weights_kernel(const float* __restrict__ Wk,
                                    const float* __restrict__ Wq,
                                    const float* __restrict__ Wv,
                                    const float* __restrict__ Ratt,
                                    const float* __restrict__ Rmsg,
                                    float* __restrict__ M) {
  int idx = blockIdx.x * 256 + threadIdx.x;
  if (idx >= NT_TYPES * M_PER_T) return;
  int t = idx / M_PER_T;
  int rem = idx % M_PER_T;
  int i = rem / M_COLS;
  int col = rem % M_COLS;
  float val;
  if (col < 64) {
    val = Wq[(size_t)t * 4096 + i * 64 + col];
  } else {
    int cc = col - 64;
    int et = cc >> 7;
    int r = cc & 127;
    int c = r >> 1;
    int half = r & 1;
    int h = c >> 4, f = c & 15;
    const float* W = half ? Wv : Wk;
    const float* R = half ? Rmsg : Ratt;
    float s = 0.f;
#pragma unroll
    for (int d = 0; d < 16; ++d)
      s = fmaf(W[(size_t)t * 4096 + i * 64 + h * 16 + d],
               R[(((size_t)h * ET_TYPES + et) * 16 + d) * 16 + f], s);
    val = s;
  }
  M[idx] = val;
}

// ---------------------------------------------------------------------------
// Build kernel: degree count (edges) + per-type node lists (nodes).
// List order is nondeterministic but per-node outputs are order-independent.
// ---------------------------------------------------------------------------
__global__ void build_kernel(const int* __restrict__ dst,
                             const int* __restrict__ ntype,
                             int* __restrict__ deg, int* __restrict__ tcnt,
                             int* __restrict__ tlist) {
  int e = blockIdx.x * 256 + threadIdx.x;
  if (e < N_EDGES) atomicAdd(&deg[dst[e]], 1);
  if (e < N_NODES) {
    int t = ntype[e];
    int pos = atomicAdd(&tcnt[t], 1);
    tlist[t * N_NODES + pos] = e;
  }
}

// ---------------------------------------------------------------------------
// Fused projection over type-lists: block (chunk, ty) holds type ty's weight
// column in 64 VGPRs; node index forced into SGPR -> x row via s_loads.
// 2-node interleave for ILP. kv outputs packed bf16x2 via shfl with partner.
// ---------------------------------------------------------------------------
__device__ __forceinline__ void proj_store(int w, int lane, int col, int n,
                                           float acc, float* __restrict__ q,
                                           unsigned int* __restrict__ kvb) {
  if (w == 0) {
    q[(size_t)n * 64 + lane] = acc;
  } else {
    float part = __shfl_xor(acc, 1, 64);   // partner column's value
    if ((lane & 1) == 0) {                 // even = katt, partner = vmsg
      int cc = col - 64;                   // 0..255, even
      int et = cc >> 7;
      int c = (cc & 127) >> 1;             // feature 0..63
      unsigned int word = f32_to_bf16(acc) | (f32_to_bf16(part) << 16);
      kvb[((size_t)et * N_NODES + n) * 64 + c] = word;
    }
  }
}

__global__ __launch_bounds__(320, 4) void fused_proj_kernel(
    const float* __restrict__ x, const float* __restrict__ M,
    const int* __restrict__ tcnt, const int* __restrict__ tlist,
    float* __restrict__ q, unsigned int* __restrict__ kvb) {
  const int w = threadIdx.x >> 6;
  const int lane = threadIdx.x & 63;
  const int col = threadIdx.x;
  const int ty = blockIdx.y;

  const int cnt = __builtin_amdgcn_readfirstlane(tcnt[ty]);
  const int i0 = blockIdx.x * PCH;
  if (i0 >= cnt) return;
  const int i1 = min(i0 + PCH, cnt);

  float wcol[64];
#pragma unroll
  for (int k = 0; k < 64; ++k)
    wcol[k] = M[(size_t)ty * M_PER_T + k * M_COLS + col];

  const int* lst = tlist + ty * N_NODES;

  int i = i0;
  for (; i + 2 <= i1; i += 2) {
    const int nA = __builtin_amdgcn_readfirstlane(lst[i]);
    const int nB = __builtin_amdgcn_readfirstlane(lst[i + 1]);
    const float* xA = x + (size_t)nA * 64;
    const float* xB = x + (size_t)nB * 64;
    float aA0 = 0.f, aA1 = 0.f, aB0 = 0.f, aB1 = 0.f;
#pragma unroll
    for (int k = 0; k < 64; k += 2) {
      aA0 = fmaf(xA[k],     wcol[k],     aA0);
      aB0 = fmaf(xB[k],     wcol[k],     aB0);
      aA1 = fmaf(xA[k + 1], wcol[k + 1], aA1);
      aB1 = fmaf(xB[k + 1], wcol[k + 1], aB1);
    }
    proj_store(w, lane, col, nA, aA0 + aA1, q, kvb);
    proj_store(w, lane, col, nB, aB0 + aB1, q, kvb);
  }
  if (i < i1) {
    const int n = __builtin_amdgcn_readfirstlane(lst[i]);
    const float* xr = x + (size_t)n * 64;
    float a0 = 0.f, a1 = 0.f;
#pragma unroll
    for (int k = 0; k < 64; k += 2) {
      a0 = fmaf(xr[k],     wcol[k],     a0);
      a1 = fmaf(xr[k + 1], wcol[k + 1], a1);
    }
    proj_store(w, lane, col, n, a0 + a1, q, kvb);
  }
}

// ---------------------------------------------------------------------------
// CSR build: 3-kernel scan + fill packed edge records.
// ---------------------------------------------------------------------------
__global__ void block_sums_kernel(const int* __restrict__ deg, int* __restrict__ bsums) {
  __shared__ int sh[256];
  int i = blockIdx.x * 256 + threadIdx.x;
  sh[threadIdx.x] = (i < N_NODES) ? deg[i] : 0;
  __syncthreads();
  for (int off = 128; off > 0; off >>= 1) {
    if (threadIdx.x < off) sh[threadIdx.x] += sh[threadIdx.x + off];
    __syncthreads();
  }
  if (threadIdx.x == 0) bsums[blockIdx.x] = sh[0];
}

__global__ void scan_sums_kernel(int* __restrict__ bsums) {
  __shared__ int sh[256];
  int t = threadIdx.x;
  sh[t] = (t < NB_SCAN) ? bsums[t] : 0;
  __syncthreads();
  for (int off = 1; off < 256; off <<= 1) {
    int v = (t >= off) ? sh[t - off] : 0;
    __syncthreads();
    sh[t] += v;
    __syncthreads();
  }
  if (t < NB_SCAN) bsums[t] = (t ? sh[t - 1] : 0);  // exclusive
}

__global__ void scan_final_kernel(const int* __restrict__ deg, const int* __restrict__ bsums,
                                  int* __restrict__ rowstart, int* __restrict__ cursor) {
  __shared__ int sh[256];
  int i = blockIdx.x * 256 + threadIdx.x;
  int t = threadIdx.x;
  sh[t] = (i < N_NODES) ? deg[i] : 0;
  __syncthreads();
  for (int off = 1; off < 256; off <<= 1) {
    int v = (t >= off) ? sh[t - off] : 0;
    __syncthreads();
    sh[t] += v;
    __syncthreads();
  }
  if (i < N_NODES) {
    int excl = (t ? sh[t - 1] : 0) + bsums[blockIdx.x];
    rowstart[i] = excl;
    cursor[i] = excl;
  }
}

// csr record: ((et*N + src) << 7) | et   -> kvb index = pk>>1, et = pk&1
__global__ void fill_csr_kernel(const int* __restrict__ src, const int* __restrict__ dst,
                                const int* __restrict__ etype, int* __restrict__ cursor,
                                int* __restrict__ csr) {
  int e = blockIdx.x * 256 + threadIdx.x;
  if (e < N_EDGES) {
    int d = dst[e];
    int et = etype[e];
    int pos = atomicAdd(&cursor[d], 1);
    csr[pos] = ((et * N_NODES + src[e]) << 7) | et;
  }
}

// ---------------------------------------------------------------------------
// Aggregation: per-dst-node exp-sum softmax (no max subtraction -- logits are
// O(0.1), mathematically identical). Node/csr control path scalarized via
// readfirstlane. Writes h into hsg (aliases q: q[n] read only by node-n's
// own wave, before its write). No LDS, no syncthreads.
// ---------------------------------------------------------------------------
__device__ __forceinline__ void edge_update(unsigned int wrd, int et, float qd,
                                            float s0, float s1,
                                            float& srun, float& acc) {
  float kw = __uint_as_float(wrd << 16);            // low bf16 = katt
  float mv = __uint_as_float(wrd & 0xFFFF0000u);    // high bf16 = vmsg
  float p = kw * qd;
  p += __shfl_xor(p, 1, 16);
  p += __shfl_xor(p, 2, 16);
  p += __shfl_xor(p, 4, 16);
  p += __shfl_xor(p, 8, 16);
  float w = __builtin_amdgcn_exp2f(p * (et ? s1 : s0));  // exp(a) via v_exp
  srun += w;
  acc = fmaf(mv, w, acc);
}

__global__ __launch_bounds__(256) void aggregate_kernel(
    const float* __restrict__ q, const unsigned int* __restrict__ kvb,
    const float* __restrict__ pri, const int* __restrict__ rowstart,
    const int* __restrict__ deg, const int* __restrict__ csr,
    float* __restrict__ hsg) {
  const int wave = threadIdx.x >> 6;
  const int lane = threadIdx.x & 63;
  int n = blockIdx.x * 4 + wave;
  if (n >= N_NODES) return;
  n = __builtin_amdgcn_readfirstlane(n);

  const int hh = lane >> 4;
  const float qd = q[(size_t)n * 64 + lane];
  const float s0 = pri[hh * ET_TYPES + 0] * 0.25f * LOG2E;
  const float s1 = pri[hh * ET_TYPES + 1] * 0.25f * LOG2E;
  const int start = __builtin_amdgcn_readfirstlane(rowstart[n]);
  const int cnt = __builtin_amdgcn_readfirstlane(deg[n]);
  const int* crow = csr + start;

  float srun = 0.f, acc = 0.f;
  int j = 0;
  for (; j + 8 <= cnt; j += 8) {
    int pk0 = __builtin_amdgcn_readfirstlane(crow[j + 0]);
    int pk1 = __builtin_amdgcn_readfirstlane(crow[j + 1]);
    int pk2 = __builtin_amdgcn_readfirstlane(crow[j + 2]);
    int pk3 = __builtin_amdgcn_readfirstlane(crow[j + 3]);
    int pk4 = __builtin_amdgcn_readfirstlane(crow[j + 4]);
    int pk5 = __builtin_amdgcn_readfirstlane(crow[j + 5]);
    int pk6 = __builtin_amdgcn_readfirstlane(crow[j + 6]);
    int pk7 = __builtin_amdgcn_readfirstlane(crow[j + 7]);
    unsigned int w0 = kvb[((unsigned)pk0 >> 1) + lane];
    unsigned int w1 = kvb[((unsigned)pk1 >> 1) + lane];
    unsigned int w2 = kvb[((unsigned)pk2 >> 1) + lane];
    unsigned int w3 = kvb[((unsigned)pk3 >> 1) + lane];
    unsigned int w4 = kvb[((unsigned)pk4 >> 1) + lane];
    unsigned int w5 = kvb[((unsigned)pk5 >> 1) + lane];
    unsigned int w6 = kvb[((unsigned)pk6 >> 1) + lane];
    unsigned int w7 = kvb[((unsigned)pk7 >> 1) + lane];
    edge_update(w0, pk0 & 1, qd, s0, s1, srun, acc);
    edge_update(w1, pk1 & 1, qd, s0, s1, srun, acc);
    edge_update(w2, pk2 & 1, qd, s0, s1, srun, acc);
    edge_update(w3, pk3 & 1, qd, s0, s1, srun, acc);
    edge_update(w4, pk4 & 1, qd, s0, s1, srun, acc);
    edge_update(w5, pk5 & 1, qd, s0, s1, srun, acc);
    edge_update(w6, pk6 & 1, qd, s0, s1, srun, acc);
    edge_update(w7, pk7 & 1, qd, s0, s1, srun, acc);
  }
  for (; j + 4 <= cnt; j += 4) {
    int pk0 = __builtin_amdgcn_readfirstlane(crow[j + 0]);
    int pk1 = __builtin_amdgcn_readfirstlane(crow[j + 1]);
    int pk2 = __builtin_amdgcn_readfirstlane(crow[j + 2]);
    int pk3 = __builtin_amdgcn_readfirstlane(crow[j + 3]);
    unsigned int w0 = kvb[((unsigned)pk0 >> 1) + lane];
    unsigned int w1 = kvb[((unsigned)pk1 >> 1) + lane];
    unsigned int w2 = kvb[((unsigned)pk2 >> 1) + lane];
    unsigned int w3 = kvb[((unsigned)pk3 >> 1) + lane];
    edge_update(w0, pk0 & 1, qd, s0, s1, srun, acc);
    edge_update(w1, pk1 & 1, qd, s0, s1, srun, acc);
    edge_update(w2, pk2 & 1, qd, s0, s1, srun, acc);
    edge_update(w3, pk3 & 1, qd, s0, s1, srun, acc);
  }
  for (; j < cnt; ++j) {
    int pk = __builtin_amdgcn_readfirstlane(crow[j]);
    unsigned int wd = kvb[((unsigned)pk >> 1) + lane];
    edge_update(wd, pk & 1, qd, s0, s1, srun, acc);
  }
  hsg[(size_t)n * 64 + lane] = (srun > 0.f) ? (acc / srun) : 0.f;
}

// ---------------------------------------------------------------------------
// Output kernel over type-lists: Wa column in 64 VGPRs, one wave per node
// (4 nodes in flight per block), h row via s_loads, sigmoid-skip blend.
// ---------------------------------------------------------------------------
__global__ __launch_bounds__(256, 4) void out_kernel(
    const float* __restrict__ hsg, const float* __restrict__ x,
    const float* __restrict__ Wa, const float* __restrict__ skip,
    const int* __restrict__ tcnt, const int* __restrict__ tlist,
    float* __restrict__ out) {
  const int w = threadIdx.x >> 6;
  const int lane = threadIdx.x & 63;
  const int ty = blockIdx.y;

  const int cnt = __builtin_amdgcn_readfirstlane(tcnt[ty]);
  const int base = blockIdx.x * OCH;
  if (base >= cnt) return;
  const int iend = min(base + OCH, cnt);

  float wcol[64];
#pragma unroll
  for (int k = 0; k < 64; ++k)
    wcol[k] = Wa[(size_t)ty * 4096 + k * 64 + lane];

  const float alpha = 1.f / (1.f + __expf(-skip[ty]));
  const float beta = 1.f - alpha;
  const int* lst = tlist + ty * N_NODES;

  for (int i = base + w; i < iend; i += 4) {
    const int n = __builtin_amdgcn_readfirstlane(lst[i]);
    const float* hr = hsg + (size_t)n * 64;
    float a0 = 0.f, a1 = 0.f, a2 = 0.f, a3 = 0.f;
#pragma unroll
    for (int k = 0; k < 64; k += 4) {
      a0 = fmaf(hr[k + 0], wcol[k + 0], a0);
      a1 = fmaf(hr[k + 1], wcol[k + 1], a1);
      a2 = fmaf(hr[k + 2], wcol[k + 2], a2);
      a3 = fmaf(hr[k + 3], wcol[k + 3], a3);
    }
    size_t o = (size_t)n * 64 + lane;
    out[o] = ((a0 + a1) + (a2 + a3)) * alpha + x[o] * beta;
  }
}

// ---------------------------------------------------------------------------
extern "C" void kernel_launch(void* const* d_in, const int* in_sizes, int n_in,
                              void* d_out, int out_size, void* d_ws, size_t ws_size,
                              hipStream_t stream) {
  const float* x    = (const float*)d_in[0];
  const float* Wk   = (const float*)d_in[1];
  const float* Wq   = (const float*)d_in[2];
  const float* Wv   = (const float*)d_in[3];
  const float* Wa   = (const float*)d_in[4];
  const float* Ratt = (const float*)d_in[5];
  const float* Rmsg = (const float*)d_in[6];
  const float* pri  = (const float*)d_in[7];
  const float* skip = (const float*)d_in[8];
  const int* ntype  = (const int*)d_in[9];
  const int* etype  = (const int*)d_in[10];
  const int* src    = (const int*)d_in[11];
  const int* dst    = (const int*)d_in[12];
  float* out = (float*)d_out;

  // workspace layout
  float* q     = (float*)d_ws;                          // N*64 floats (also hsg)
  unsigned int* kvb = (unsigned int*)(q + (size_t)N_NODES * 64);  // ET*N*64 dwords
  int* rowstart = (int*)(kvb + (size_t)ET_TYPES * N_NODES * 64);  // N
  int* deg      = rowstart + N_NODES;                   // N   (memset with tcnt)
  int* tcnt     = deg + N_NODES;                        // 2
  int* cursor   = tcnt + 2;                             // N
  int* tlist    = cursor + N_NODES;                     // 2*N
  int* csr      = tlist + 2 * N_NODES;                  // E
  int* bsums    = csr + N_EDGES;                        // NB_SCAN (<=256)
  float* M      = (float*)(bsums + 256);                // NT*64*320 floats
  float* hsg    = q;                                    // alias (safe, see agg)

  hipMemsetAsync(deg, 0, (N_NODES + 2) * sizeof(int), stream);

  fold_weights_kernel<<<(NT_TYPES * M_PER_T + 255) / 256, 256, 0, stream>>>(
      Wk, Wq, Wv, Ratt, Rmsg, M);

  build_kernel<<<(N_EDGES + 255) / 256, 256, 0, stream>>>(
      dst, ntype, deg, tcnt, tlist);

  dim3 pgrid((N_NODES + PCH - 1) / PCH, NT_TYPES);
  fused_proj_kernel<<<pgrid, 320, 0, stream>>>(x, M, tcnt, tlist, q, kvb);

  block_sums_kernel<<<NB_SCAN, 256, 0, stream>>>(deg, bsums);
  scan_sums_kernel<<<1, 256, 0, stream>>>(bsums);
  scan_final_kernel<<<NB_SCAN, 256, 0, stream>>>(deg, bsums, rowstart, cursor);
  fill_csr_kernel<<<(N_EDGES + 255) / 256, 256, 0, stream>>>(src, dst, etype, cursor, csr);

  aggregate_kernel<<<(N_NODES + 3) / 4, 256, 0, stream>>>(
      (const float*)q, (const unsigned int*)kvb, pri, rowstart, deg, csr, hsg);

  dim3 ogrid((N_NODES + OCH - 1) / OCH, NT_TYPES);
  out_kernel<<<ogrid, 256, 0, stream>>>(hsg, x, Wa, skip, tcnt, tlist, out);
}

// Round 8
// 237.003 us; speedup vs baseline: 2.5456x; 2.5456x over previous
//
#include <hip/hip_runtime.h>
#include <math.h>

#define N_NODES 50000
#define N_EDGES 800000
#define IN_DIM 64
#define H_HEADS 4
#define D_HEAD 16
#define NT_TYPES 2
#define ET_TYPES 2
#define HD 64
#define NB_SCAN ((N_NODES + 255) / 256)   // 196
#define M_COLS 320                         // 64 q + 2et*128 interleaved (katt,vmsg)
#define M_PER_T (64 * M_COLS)              // 20480 floats per type
#define PCH 50                             // proj: type-list entries per block
#define OCH 100                            // out: type-list entries per block
#define LOG2E 1.44269504088896f

__device__ __forceinline__ unsigned int f32_to_bf16(float f) {
  unsigned int u = __float_as_uint(f);
  return (u + 0x7FFFu + ((u >> 16) & 1u)) >> 16;   // RNE
}

// ---------------------------------------------------------------------------
// Fold kernel: M[t][i][col] such that  y[n] = x[n] @ M[ntype[n]]  yields
//   col 0..63            -> q[n][col]
//   col 64+cc, et=cc>>7, r=cc&127, c=r>>1, half=r&1
//                        -> half==0: katt[et][n][c] ; half==1: vmsg[et][n][c]
// ---------------------------------------------------------------------------
__global__ void fold_weights_kernel(const float* __restrict__ Wk,
                                    const float* __restrict__ Wq,
                                    const float* __restrict__ Wv,
                                    const float* __restrict__ Ratt,
                                    const float* __restrict__ Rmsg,
                                    float* __restrict__ M) {
  int idx = blockIdx.x * 256 + threadIdx.x;
  if (idx >= NT_TYPES * M_PER_T) return;
  int t = idx / M_PER_T;
  int rem = idx % M_PER_T;
  int i = rem / M_COLS;
  int col = rem % M_COLS;
  float val;
  if (col < 64) {
    val = Wq[(size_t)t * 4096 + i * 64 + col];
  } else {
    int cc = col - 64;
    int et = cc >> 7;
    int r = cc & 127;
    int c = r >> 1;
    int half = r & 1;
    int h = c >> 4, f = c & 15;
    const float* W = half ? Wv : Wk;
    const float* R = half ? Rmsg : Ratt;
    float s = 0.f;
#pragma unroll
    for (int d = 0; d < 16; ++d)
      s = fmaf(W[(size_t)t * 4096 + i * 64 + h * 16 + d],
               R[(((size_t)h * ET_TYPES + et) * 16 + d) * 16 + f], s);
    val = s;
  }
  M[idx] = val;
}

// ---------------------------------------------------------------------------
// Degree count (edge-parallel). 800k atomics over 50k addresses: fine.
// ---------------------------------------------------------------------------
__global__ void count_deg_kernel(const int* __restrict__ dst, int* __restrict__ deg) {
  int e = blockIdx.x * 256 + threadIdx.x;
  if (e < N_EDGES) atomicAdd(&deg[dst[e]], 1);
}

// ---------------------------------------------------------------------------
// Type-list build with per-block LDS aggregation: 256 LDS atomics/block,
// then ONE global atomicAdd per (block, type) to reserve a range.
// (Round-7 lesson: 50k global atomics on 2 addresses = 408us. This: 392.)
// ---------------------------------------------------------------------------
__global__ void typelist_kernel(const int* __restrict__ ntype,
                                int* __restrict__ tcnt, int* __restrict__ tlist) {
  __shared__ int lcnt[NT_TYPES];
  __shared__ int lbase[NT_TYPES];
  const int i = blockIdx.x * 256 + threadIdx.x;
  if (threadIdx.x < NT_TYPES) lcnt[threadIdx.x] = 0;
  __syncthreads();
  int t = 0, lpos = 0;
  const bool valid = (i < N_NODES);
  if (valid) {
    t = ntype[i];
    lpos = atomicAdd(&lcnt[t], 1);          // LDS atomic
  }
  __syncthreads();
  if (threadIdx.x < NT_TYPES)
    lbase[threadIdx.x] = atomicAdd(&tcnt[threadIdx.x], lcnt[threadIdx.x]);
  __syncthreads();
  if (valid)
    tlist[t * N_NODES + lbase[t] + lpos] = i;
}

// ---------------------------------------------------------------------------
// Fused projection over type-lists: block (chunk, ty) holds type ty's weight
// column in 64 VGPRs; node index forced into SGPR -> x row via s_loads.
// 2-node interleave for ILP. kv outputs packed bf16x2 via shfl with partner.
// ---------------------------------------------------------------------------
__device__ __forceinline__ void proj_store(int w, int lane, int col, int n,
                                           float acc, float* __restrict__ q,
                                           unsigned int* __restrict__ kvb) {
  if (w == 0) {
    q[(size_t)n * 64 + lane] = acc;
  } else {
    float part = __shfl_xor(acc, 1, 64);   // partner column's value
    if ((lane & 1) == 0) {                 // even = katt, partner = vmsg
      int cc = col - 64;                   // 0..255, even
      int et = cc >> 7;
      int c = (cc & 127) >> 1;             // feature 0..63
      unsigned int word = f32_to_bf16(acc) | (f32_to_bf16(part) << 16);
      kvb[((size_t)et * N_NODES + n) * 64 + c] = word;
    }
  }
}

__global__ __launch_bounds__(320, 4) void fused_proj_kernel(
    const float* __restrict__ x, const float* __restrict__ M,
    const int* __restrict__ tcnt, const int* __restrict__ tlist,
    float* __restrict__ q, unsigned int* __restrict__ kvb) {
  const int w = threadIdx.x >> 6;
  const int lane = threadIdx.x & 63;
  const int col = threadIdx.x;
  const int ty = blockIdx.y;

  const int cnt = __builtin_amdgcn_readfirstlane(tcnt[ty]);
  const int i0 = blockIdx.x * PCH;
  if (i0 >= cnt) return;
  const int i1 = min(i0 + PCH, cnt);

  float wcol[64];
#pragma unroll
  for (int k = 0; k < 64; ++k)
    wcol[k] = M[(size_t)ty * M_PER_T + k * M_COLS + col];

  const int* lst = tlist + ty * N_NODES;

  int i = i0;
  for (; i + 2 <= i1; i += 2) {
    const int nA = __builtin_amdgcn_readfirstlane(lst[i]);
    const int nB = __builtin_amdgcn_readfirstlane(lst[i + 1]);
    const float* xA = x + (size_t)nA * 64;
    const float* xB = x + (size_t)nB * 64;
    float aA0 = 0.f, aA1 = 0.f, aB0 = 0.f, aB1 = 0.f;
#pragma unroll
    for (int k = 0; k < 64; k += 2) {
      aA0 = fmaf(xA[k],     wcol[k],     aA0);
      aB0 = fmaf(xB[k],     wcol[k],     aB0);
      aA1 = fmaf(xA[k + 1], wcol[k + 1], aA1);
      aB1 = fmaf(xB[k + 1], wcol[k + 1], aB1);
    }
    proj_store(w, lane, col, nA, aA0 + aA1, q, kvb);
    proj_store(w, lane, col, nB, aB0 + aB1, q, kvb);
  }
  if (i < i1) {
    const int n = __builtin_amdgcn_readfirstlane(lst[i]);
    const float* xr = x + (size_t)n * 64;
    float a0 = 0.f, a1 = 0.f;
#pragma unroll
    for (int k = 0; k < 64; k += 2) {
      a0 = fmaf(xr[k],     wcol[k],     a0);
      a1 = fmaf(xr[k + 1], wcol[k + 1], a1);
    }
    proj_store(w, lane, col, n, a0 + a1, q, kvb);
  }
}

// ---------------------------------------------------------------------------
// CSR build: 3-kernel scan + fill packed edge records.
// ---------------------------------------------------------------------------
__global__ void block_sums_kernel(const int* __restrict__ deg, int* __restrict__ bsums) {
  __shared__ int sh[256];
  int i = blockIdx.x * 256 + threadIdx.x;
  sh[threadIdx.x] = (i < N_NODES) ? deg[i] : 0;
  __syncthreads();
  for (int off = 128; off > 0; off >>= 1) {
    if (threadIdx.x < off) sh[threadIdx.x] += sh[threadIdx.x + off];
    __syncthreads();
  }
  if (threadIdx.x == 0) bsums[blockIdx.x] = sh[0];
}

__global__ void scan_sums_kernel(int* __restrict__ bsums) {
  __shared__ int sh[256];
  int t = threadIdx.x;
  sh[t] = (t < NB_SCAN) ? bsums[t] : 0;
  __syncthreads();
  for (int off = 1; off < 256; off <<= 1) {
    int v = (t >= off) ? sh[t - off] : 0;
    __syncthreads();
    sh[t] += v;
    __syncthreads();
  }
  if (t < NB_SCAN) bsums[t] = (t ? sh[t - 1] : 0);  // exclusive
}

__global__ void scan_final_kernel(const int* __restrict__ deg, const int* __restrict__ bsums,
                                  int* __restrict__ rowstart, int* __restrict__ cursor) {
  __shared__ int sh[256];
  int i = blockIdx.x * 256 + threadIdx.x;
  int t = threadIdx.x;
  sh[t] = (i < N_NODES) ? deg[i] : 0;
  __syncthreads();
  for (int off = 1; off < 256; off <<= 1) {
    int v = (t >= off) ? sh[t - off] : 0;
    __syncthreads();
    sh[t] += v;
    __syncthreads();
  }
  if (i < N_NODES) {
    int excl = (t ? sh[t - 1] : 0) + bsums[blockIdx.x];
    rowstart[i] = excl;
    cursor[i] = excl;
  }
}

// csr record: ((et*N + src) << 7) | et   -> kvb index = pk>>1, et = pk&1
__global__ void fill_csr_kernel(const int* __restrict__ src, const int* __restrict__ dst,
                                const int* __restrict__ etype, int* __restrict__ cursor,
                                int* __restrict__ csr) {
  int e = blockIdx.x * 256 + threadIdx.x;
  if (e < N_EDGES) {
    int d = dst[e];
    int et = etype[e];
    int pos = atomicAdd(&cursor[d], 1);
    csr[pos] = ((et * N_NODES + src[e]) << 7) | et;
  }
}

// ---------------------------------------------------------------------------
// Aggregation: per-dst-node exp-sum softmax (no max subtraction -- logits are
// O(0.1), mathematically identical). Node/csr control path scalarized via
// readfirstlane. Writes h into hsg (aliases q: q[n] read only by node-n's
// own wave, before its write). No LDS, no syncthreads.
// ---------------------------------------------------------------------------
__device__ __forceinline__ void edge_update(unsigned int wrd, int et, float qd,
                                            float s0, float s1,
                                            float& srun, float& acc) {
  float kw = __uint_as_float(wrd << 16);            // low bf16 = katt
  float mv = __uint_as_float(wrd & 0xFFFF0000u);    // high bf16 = vmsg
  float p = kw * qd;
  p += __shfl_xor(p, 1, 16);
  p += __shfl_xor(p, 2, 16);
  p += __shfl_xor(p, 4, 16);
  p += __shfl_xor(p, 8, 16);
  float w = __builtin_amdgcn_exp2f(p * (et ? s1 : s0));  // exp(a) via v_exp
  srun += w;
  acc = fmaf(mv, w, acc);
}

__global__ __launch_bounds__(256) void aggregate_kernel(
    const float* __restrict__ q, const unsigned int* __restrict__ kvb,
    const float* __restrict__ pri, const int* __restrict__ rowstart,
    const int* __restrict__ deg, const int* __restrict__ csr,
    float* __restrict__ hsg) {
  const int wave = threadIdx.x >> 6;
  const int lane = threadIdx.x & 63;
  int n = blockIdx.x * 4 + wave;
  if (n >= N_NODES) return;
  n = __builtin_amdgcn_readfirstlane(n);

  const int hh = lane >> 4;
  const float qd = q[(size_t)n * 64 + lane];
  const float s0 = pri[hh * ET_TYPES + 0] * 0.25f * LOG2E;
  const float s1 = pri[hh * ET_TYPES + 1] * 0.25f * LOG2E;
  const int start = __builtin_amdgcn_readfirstlane(rowstart[n]);
  const int cnt = __builtin_amdgcn_readfirstlane(deg[n]);
  const int* crow = csr + start;

  float srun = 0.f, acc = 0.f;
  int j = 0;
  for (; j + 8 <= cnt; j += 8) {
    int pk0 = __builtin_amdgcn_readfirstlane(crow[j + 0]);
    int pk1 = __builtin_amdgcn_readfirstlane(crow[j + 1]);
    int pk2 = __builtin_amdgcn_readfirstlane(crow[j + 2]);
    int pk3 = __builtin_amdgcn_readfirstlane(crow[j + 3]);
    int pk4 = __builtin_amdgcn_readfirstlane(crow[j + 4]);
    int pk5 = __builtin_amdgcn_readfirstlane(crow[j + 5]);
    int pk6 = __builtin_amdgcn_readfirstlane(crow[j + 6]);
    int pk7 = __builtin_amdgcn_readfirstlane(crow[j + 7]);
    unsigned int w0 = kvb[((unsigned)pk0 >> 1) + lane];
    unsigned int w1 = kvb[((unsigned)pk1 >> 1) + lane];
    unsigned int w2 = kvb[((unsigned)pk2 >> 1) + lane];
    unsigned int w3 = kvb[((unsigned)pk3 >> 1) + lane];
    unsigned int w4 = kvb[((unsigned)pk4 >> 1) + lane];
    unsigned int w5 = kvb[((unsigned)pk5 >> 1) + lane];
    unsigned int w6 = kvb[((unsigned)pk6 >> 1) + lane];
    unsigned int w7 = kvb[((unsigned)pk7 >> 1) + lane];
    edge_update(w0, pk0 & 1, qd, s0, s1, srun, acc);
    edge_update(w1, pk1 & 1, qd, s0, s1, srun, acc);
    edge_update(w2, pk2 & 1, qd, s0, s1, srun, acc);
    edge_update(w3, pk3 & 1, qd, s0, s1, srun, acc);
    edge_update(w4, pk4 & 1, qd, s0, s1, srun, acc);
    edge_update(w5, pk5 & 1, qd, s0, s1, srun, acc);
    edge_update(w6, pk6 & 1, qd, s0, s1, srun, acc);
    edge_update(w7, pk7 & 1, qd, s0, s1, srun, acc);
  }
  for (; j + 4 <= cnt; j += 4) {
    int pk0 = __builtin_amdgcn_readfirstlane(crow[j + 0]);
    int pk1 = __builtin_amdgcn_readfirstlane(crow[j + 1]);
    int pk2 = __builtin_amdgcn_readfirstlane(crow[j + 2]);
    int pk3 = __builtin_amdgcn_readfirstlane(crow[j + 3]);
    unsigned int w0 = kvb[((unsigned)pk0 >> 1) + lane];
    unsigned int w1 = kvb[((unsigned)pk1 >> 1) + lane];
    unsigned int w2 = kvb[((unsigned)pk2 >> 1) + lane];
    unsigned int w3 = kvb[((unsigned)pk3 >> 1) + lane];
    edge_update(w0, pk0 & 1, qd, s0, s1, srun, acc);
    edge_update(w1, pk1 & 1, qd, s0, s1, srun, acc);
    edge_update(w2, pk2 & 1, qd, s0, s1, srun, acc);
    edge_update(w3, pk3 & 1, qd, s0, s1, srun, acc);
  }
  for (; j < cnt; ++j) {
    int pk = __builtin_amdgcn_readfirstlane(crow[j]);
    unsigned int wd = kvb[((unsigned)pk >> 1) + lane];
    edge_update(wd, pk & 1, qd, s0, s1, srun, acc);
  }
  hsg[(size_t)n * 64 + lane] = (srun > 0.f) ? (acc / srun) : 0.f;
}

// ---------------------------------------------------------------------------
// Output kernel over type-lists: Wa column in 64 VGPRs, one wave per node
// (4 nodes in flight per block), h row via s_loads, sigmoid-skip blend.
// ---------------------------------------------------------------------------
__global__ __launch_bounds__(256, 4) void out_kernel(
    const float* __restrict__ hsg, const float* __restrict__ x,
    const float* __restrict__ Wa, const float* __restrict__ skip,
    const int* __restrict__ tcnt, const int* __restrict__ tlist,
    float* __restrict__ out) {
  const int w = threadIdx.x >> 6;
  const int lane = threadIdx.x & 63;
  const int ty = blockIdx.y;

  const int cnt = __builtin_amdgcn_readfirstlane(tcnt[ty]);
  const int base = blockIdx.x * OCH;
  if (base >= cnt) return;
  const int iend = min(base + OCH, cnt);

  float wcol[64];
#pragma unroll
  for (int k = 0; k < 64; ++k)
    wcol[k] = Wa[(size_t)ty * 4096 + k * 64 + lane];

  const float alpha = 1.f / (1.f + __expf(-skip[ty]));
  const float beta = 1.f - alpha;
  const int* lst = tlist + ty * N_NODES;

  for (int i = base + w; i < iend; i += 4) {
    const int n = __builtin_amdgcn_readfirstlane(lst[i]);
    const float* hr = hsg + (size_t)n * 64;
    float a0 = 0.f, a1 = 0.f, a2 = 0.f, a3 = 0.f;
#pragma unroll
    for (int k = 0; k < 64; k += 4) {
      a0 = fmaf(hr[k + 0], wcol[k + 0], a0);
      a1 = fmaf(hr[k + 1], wcol[k + 1], a1);
      a2 = fmaf(hr[k + 2], wcol[k + 2], a2);
      a3 = fmaf(hr[k + 3], wcol[k + 3], a3);
    }
    size_t o = (size_t)n * 64 + lane;
    out[o] = ((a0 + a1) + (a2 + a3)) * alpha + x[o] * beta;
  }
}

// ---------------------------------------------------------------------------
extern "C" void kernel_launch(void* const* d_in, const int* in_sizes, int n_in,
                              void* d_out, int out_size, void* d_ws, size_t ws_size,
                              hipStream_t stream) {
  const float* x    = (const float*)d_in[0];
  const float* Wk   = (const float*)d_in[1];
  const float* Wq   = (const float*)d_in[2];
  const float* Wv   = (const float*)d_in[3];
  const float* Wa   = (const float*)d_in[4];
  const float* Ratt = (const float*)d_in[5];
  const float* Rmsg = (const float*)d_in[6];
  const float* pri  = (const float*)d_in[7];
  const float* skip = (const float*)d_in[8];
  const int* ntype  = (const int*)d_in[9];
  const int* etype  = (const int*)d_in[10];
  const int* src    = (const int*)d_in[11];
  const int* dst    = (const int*)d_in[12];
  float* out = (float*)d_out;

  // workspace layout
  float* q     = (float*)d_ws;                          // N*64 floats (also hsg)
  unsigned int* kvb = (unsigned int*)(q + (size_t)N_NODES * 64);  // ET*N*64 dwords
  int* rowstart = (int*)(kvb + (size_t)ET_TYPES * N_NODES * 64);  // N
  int* deg      = rowstart + N_NODES;                   // N   (memset with tcnt)
  int* tcnt     = deg + N_NODES;                        // 2
  int* cursor   = tcnt + 2;                             // N
  int* tlist    = cursor + N_NODES;                     // 2*N
  int* csr      = tlist + 2 * N_NODES;                  // E
  int* bsums    = csr + N_EDGES;                        // NB_SCAN (<=256)
  float* M      = (float*)(bsums + 256);                // NT*64*320 floats
  float* hsg    = q;                                    // alias (safe, see agg)

  hipMemsetAsync(deg, 0, (N_NODES + 2) * sizeof(int), stream);

  fold_weights_kernel<<<(NT_TYPES * M_PER_T + 255) / 256, 256, 0, stream>>>(
      Wk, Wq, Wv, Ratt, Rmsg, M);

  count_deg_kernel<<<(N_EDGES + 255) / 256, 256, 0, stream>>>(dst, deg);
  typelist_kernel<<<NB_SCAN, 256, 0, stream>>>(ntype, tcnt, tlist);

  dim3 pgrid((N_NODES + PCH - 1) / PCH, NT_TYPES);
  fused_proj_kernel<<<pgrid, 320, 0, stream>>>(x, M, tcnt, tlist, q, kvb);

  block_sums_kernel<<<NB_SCAN, 256, 0, stream>>>(deg, bsums);
  scan_sums_kernel<<<1, 256, 0, stream>>>(bsums);
  scan_final_kernel<<<NB_SCAN, 256, 0, stream>>>(deg, bsums, rowstart, cursor);
  fill_csr_kernel<<<(N_EDGES + 255) / 256, 256, 0, stream>>>(src, dst, etype, cursor, csr);

  aggregate_kernel<<<(N_NODES + 3) / 4, 256, 0, stream>>>(
      (const float*)q, (const unsigned int*)kvb, pri, rowstart, deg, csr, hsg);

  dim3 ogrid((N_NODES + OCH - 1) / OCH, NT_TYPES);
  out_kernel<<<ogrid, 256, 0, stream>>>(hsg, x, Wa, skip, tcnt, tlist, out);
}

// Round 9
// 225.210 us; speedup vs baseline: 2.6789x; 1.0524x over previous
//
#include <hip/hip_runtime.h>
#include <math.h>

#define N_NODES 50000
#define N_EDGES 800000
#define IN_DIM 64
#define H_HEADS 4
#define D_HEAD 16
#define NT_TYPES 2
#define ET_TYPES 2
#define HD 64
#define NB_SCAN ((N_NODES + 255) / 256)   // 196
#define M_COLS 320                         // 64 q + 2et*128 interleaved (katt,vmsg)
#define M_PER_T (64 * M_COLS)              // 20480 floats per type
#define PCH 50                             // proj: type-list entries per block
#define OCH 100                            // out: type-list entries per block
#define LOG2E 1.44269504088896f

__device__ __forceinline__ unsigned int f32_to_bf16(float f) {
  unsigned int u = __float_as_uint(f);
  return (u + 0x7FFFu + ((u >> 16) & 1u)) >> 16;   // RNE
}

// ---------------------------------------------------------------------------
// Prep kernel (merged): fold weights into M + zero deg/tcnt.
//   M[t][i][col]: col 0..63 -> q; col 64+cc: et=cc>>7, r=cc&127, c=r>>1,
//   half=r&1 -> half0: katt[et][n][c], half1: vmsg[et][n][c].
// Grid: NB_SCAN blocks x 256 covers both N_NODES and NT*M_PER_T index spaces.
// ---------------------------------------------------------------------------
__global__ void prep_kernel(const float* __restrict__ Wk,
                            const float* __restrict__ Wq,
                            const float* __restrict__ Wv,
                            const float* __restrict__ Ratt,
                            const float* __restrict__ Rmsg,
                            float* __restrict__ M,
                            int* __restrict__ deg, int* __restrict__ tcnt) {
  int idx = blockIdx.x * 256 + threadIdx.x;
  if (idx < N_NODES) deg[idx] = 0;
  if (idx < NT_TYPES) tcnt[idx] = 0;
  if (idx < NT_TYPES * M_PER_T) {
    int t = idx / M_PER_T;
    int rem = idx % M_PER_T;
    int i = rem / M_COLS;
    int col = rem % M_COLS;
    float val;
    if (col < 64) {
      val = Wq[(size_t)t * 4096 + i * 64 + col];
    } else {
      int cc = col - 64;
      int et = cc >> 7;
      int r = cc & 127;
      int c = r >> 1;
      int half = r & 1;
      int h = c >> 4, f = c & 15;
      const float* W = half ? Wv : Wk;
      const float* R = half ? Rmsg : Ratt;
      float s = 0.f;
#pragma unroll
      for (int d = 0; d < 16; ++d)
        s = fmaf(W[(size_t)t * 4096 + i * 64 + h * 16 + d],
                 R[(((size_t)h * ET_TYPES + et) * 16 + d) * 16 + f], s);
      val = s;
    }
    M[idx] = val;
  }
}

// ---------------------------------------------------------------------------
// Build kernel (merged): edge-parallel degree count + node-parallel type
// lists with per-block LDS aggregation (one global atomic per block,type).
// ---------------------------------------------------------------------------
__global__ void build_kernel(const int* __restrict__ dst,
                             const int* __restrict__ ntype,
                             int* __restrict__ deg, int* __restrict__ tcnt,
                             int* __restrict__ tlist) {
  const int e = blockIdx.x * 256 + threadIdx.x;
  if (e < N_EDGES) atomicAdd(&deg[dst[e]], 1);
  if (blockIdx.x < NB_SCAN) {
    __shared__ int lcnt[NT_TYPES];
    __shared__ int lbase[NT_TYPES];
    if (threadIdx.x < NT_TYPES) lcnt[threadIdx.x] = 0;
    __syncthreads();
    int t = 0, lpos = 0;
    const bool valid = (e < N_NODES);
    if (valid) {
      t = ntype[e];
      lpos = atomicAdd(&lcnt[t], 1);        // LDS atomic
    }
    __syncthreads();
    if (threadIdx.x < NT_TYPES)
      lbase[threadIdx.x] = atomicAdd(&tcnt[threadIdx.x], lcnt[threadIdx.x]);
    __syncthreads();
    if (valid)
      tlist[t * N_NODES + lbase[t] + lpos] = e;
  }
}

// ---------------------------------------------------------------------------
// Fused projection over type-lists: block (chunk, ty) holds type ty's weight
// column in 64 VGPRs; node index forced into SGPR -> x row via s_loads.
// SINGLE node per iteration (R8 lesson: 2-node interleave = 2x64 SGPR x-rows
// -> SGPR pressure -> wcol demoted, VGPR_Count 40, 72us).
// ---------------------------------------------------------------------------
__device__ __forceinline__ void proj_store(int w, int lane, int col, int n,
                                           float acc, float* __restrict__ q,
                                           unsigned int* __restrict__ kvb) {
  if (w == 0) {
    q[(size_t)n * 64 + lane] = acc;
  } else {
    float part = __shfl_xor(acc, 1, 64);   // partner column's value
    if ((lane & 1) == 0) {                 // even = katt, partner = vmsg
      int cc = col - 64;                   // 0..255, even
      int et = cc >> 7;
      int c = (cc & 127) >> 1;             // feature 0..63
      unsigned int word = f32_to_bf16(acc) | (f32_to_bf16(part) << 16);
      kvb[((size_t)et * N_NODES + n) * 64 + c] = word;
    }
  }
}

__global__ __launch_bounds__(320, 4) void fused_proj_kernel(
    const float* __restrict__ x, const float* __restrict__ M,
    const int* __restrict__ tcnt, const int* __restrict__ tlist,
    float* __restrict__ q, unsigned int* __restrict__ kvb) {
  const int w = threadIdx.x >> 6;
  const int lane = threadIdx.x & 63;
  const int col = threadIdx.x;
  const int ty = blockIdx.y;

  const int cnt = __builtin_amdgcn_readfirstlane(tcnt[ty]);
  const int i0 = blockIdx.x * PCH;
  if (i0 >= cnt) return;
  const int i1 = min(i0 + PCH, cnt);

  float wcol[64];
#pragma unroll
  for (int k = 0; k < 64; ++k)
    wcol[k] = M[(size_t)ty * M_PER_T + k * M_COLS + col];

  const int* lst = tlist + ty * N_NODES;

  for (int i = i0; i < i1; ++i) {
    const int n = __builtin_amdgcn_readfirstlane(lst[i]);
    const float* xr = x + (size_t)n * 64;   // scalar row (s_loads)
    float a0 = 0.f, a1 = 0.f, a2 = 0.f, a3 = 0.f;
#pragma unroll
    for (int k = 0; k < 64; k += 4) {
      a0 = fmaf(xr[k + 0], wcol[k + 0], a0);
      a1 = fmaf(xr[k + 1], wcol[k + 1], a1);
      a2 = fmaf(xr[k + 2], wcol[k + 2], a2);
      a3 = fmaf(xr[k + 3], wcol[k + 3], a3);
    }
    proj_store(w, lane, col, n, (a0 + a1) + (a2 + a3), q, kvb);
  }
}

// ---------------------------------------------------------------------------
// CSR build: 3-kernel scan + fill packed edge records.
// ---------------------------------------------------------------------------
__global__ void block_sums_kernel(const int* __restrict__ deg, int* __restrict__ bsums) {
  __shared__ int sh[256];
  int i = blockIdx.x * 256 + threadIdx.x;
  sh[threadIdx.x] = (i < N_NODES) ? deg[i] : 0;
  __syncthreads();
  for (int off = 128; off > 0; off >>= 1) {
    if (threadIdx.x < off) sh[threadIdx.x] += sh[threadIdx.x + off];
    __syncthreads();
  }
  if (threadIdx.x == 0) bsums[blockIdx.x] = sh[0];
}

__global__ void scan_sums_kernel(int* __restrict__ bsums) {
  __shared__ int sh[256];
  int t = threadIdx.x;
  sh[t] = (t < NB_SCAN) ? bsums[t] : 0;
  __syncthreads();
  for (int off = 1; off < 256; off <<= 1) {
    int v = (t >= off) ? sh[t - off] : 0;
    __syncthreads();
    sh[t] += v;
    __syncthreads();
  }
  if (t < NB_SCAN) bsums[t] = (t ? sh[t - 1] : 0);  // exclusive
}

__global__ void scan_final_kernel(const int* __restrict__ deg, const int* __restrict__ bsums,
                                  int* __restrict__ rowstart, int* __restrict__ cursor) {
  __shared__ int sh[256];
  int i = blockIdx.x * 256 + threadIdx.x;
  int t = threadIdx.x;
  sh[t] = (i < N_NODES) ? deg[i] : 0;
  __syncthreads();
  for (int off = 1; off < 256; off <<= 1) {
    int v = (t >= off) ? sh[t - off] : 0;
    __syncthreads();
    sh[t] += v;
    __syncthreads();
  }
  if (i < N_NODES) {
    int excl = (t ? sh[t - 1] : 0) + bsums[blockIdx.x];
    rowstart[i] = excl;
    cursor[i] = excl;
  }
}

// csr record: ((et*N + src) << 7) | et   -> kvb index = pk>>1, et = pk&1
__global__ void fill_csr_kernel(const int* __restrict__ src, const int* __restrict__ dst,
                                const int* __restrict__ etype, int* __restrict__ cursor,
                                int* __restrict__ csr) {
  int e = blockIdx.x * 256 + threadIdx.x;
  if (e < N_EDGES) {
    int d = dst[e];
    int et = etype[e];
    int pos = atomicAdd(&cursor[d], 1);
    csr[pos] = ((et * N_NODES + src[e]) << 7) | et;
  }
}

// ---------------------------------------------------------------------------
// Aggregation: per-dst-node exp-sum softmax (no max subtraction -- logits are
// O(0.1), mathematically identical). Node/csr control path scalarized via
// readfirstlane. Writes h into hsg (aliases q: q[n] read only by node-n's
// own wave, before its write). No LDS, no syncthreads.
// ---------------------------------------------------------------------------
__device__ __forceinline__ void edge_update(unsigned int wrd, int et, float qd,
                                            float s0, float s1,
                                            float& srun, float& acc) {
  float kw = __uint_as_float(wrd << 16);            // low bf16 = katt
  float mv = __uint_as_float(wrd & 0xFFFF0000u);    // high bf16 = vmsg
  float p = kw * qd;
  p += __shfl_xor(p, 1, 16);
  p += __shfl_xor(p, 2, 16);
  p += __shfl_xor(p, 4, 16);
  p += __shfl_xor(p, 8, 16);
  float w = __builtin_amdgcn_exp2f(p * (et ? s1 : s0));  // exp(a) via v_exp
  srun += w;
  acc = fmaf(mv, w, acc);
}

__global__ __launch_bounds__(256) void aggregate_kernel(
    const float* __restrict__ q, const unsigned int* __restrict__ kvb,
    const float* __restrict__ pri, const int* __restrict__ rowstart,
    const int* __restrict__ deg, const int* __restrict__ csr,
    float* __restrict__ hsg) {
  const int wave = threadIdx.x >> 6;
  const int lane = threadIdx.x & 63;
  int n = blockIdx.x * 4 + wave;
  if (n >= N_NODES) return;
  n = __builtin_amdgcn_readfirstlane(n);

  const int hh = lane >> 4;
  const float qd = q[(size_t)n * 64 + lane];
  const float s0 = pri[hh * ET_TYPES + 0] * 0.25f * LOG2E;
  const float s1 = pri[hh * ET_TYPES + 1] * 0.25f * LOG2E;
  const int start = __builtin_amdgcn_readfirstlane(rowstart[n]);
  const int cnt = __builtin_amdgcn_readfirstlane(deg[n]);
  const int* crow = csr + start;

  float srun = 0.f, acc = 0.f;
  int j = 0;
  for (; j + 8 <= cnt; j += 8) {
    int pk0 = __builtin_amdgcn_readfirstlane(crow[j + 0]);
    int pk1 = __builtin_amdgcn_readfirstlane(crow[j + 1]);
    int pk2 = __builtin_amdgcn_readfirstlane(crow[j + 2]);
    int pk3 = __builtin_amdgcn_readfirstlane(crow[j + 3]);
    int pk4 = __builtin_amdgcn_readfirstlane(crow[j + 4]);
    int pk5 = __builtin_amdgcn_readfirstlane(crow[j + 5]);
    int pk6 = __builtin_amdgcn_readfirstlane(crow[j + 6]);
    int pk7 = __builtin_amdgcn_readfirstlane(crow[j + 7]);
    unsigned int w0 = kvb[((unsigned)pk0 >> 1) + lane];
    unsigned int w1 = kvb[((unsigned)pk1 >> 1) + lane];
    unsigned int w2 = kvb[((unsigned)pk2 >> 1) + lane];
    unsigned int w3 = kvb[((unsigned)pk3 >> 1) + lane];
    unsigned int w4 = kvb[((unsigned)pk4 >> 1) + lane];
    unsigned int w5 = kvb[((unsigned)pk5 >> 1) + lane];
    unsigned int w6 = kvb[((unsigned)pk6 >> 1) + lane];
    unsigned int w7 = kvb[((unsigned)pk7 >> 1) + lane];
    edge_update(w0, pk0 & 1, qd, s0, s1, srun, acc);
    edge_update(w1, pk1 & 1, qd, s0, s1, srun, acc);
    edge_update(w2, pk2 & 1, qd, s0, s1, srun, acc);
    edge_update(w3, pk3 & 1, qd, s0, s1, srun, acc);
    edge_update(w4, pk4 & 1, qd, s0, s1, srun, acc);
    edge_update(w5, pk5 & 1, qd, s0, s1, srun, acc);
    edge_update(w6, pk6 & 1, qd, s0, s1, srun, acc);
    edge_update(w7, pk7 & 1, qd, s0, s1, srun, acc);
  }
  for (; j + 4 <= cnt; j += 4) {
    int pk0 = __builtin_amdgcn_readfirstlane(crow[j + 0]);
    int pk1 = __builtin_amdgcn_readfirstlane(crow[j + 1]);
    int pk2 = __builtin_amdgcn_readfirstlane(crow[j + 2]);
    int pk3 = __builtin_amdgcn_readfirstlane(crow[j + 3]);
    unsigned int w0 = kvb[((unsigned)pk0 >> 1) + lane];
    unsigned int w1 = kvb[((unsigned)pk1 >> 1) + lane];
    unsigned int w2 = kvb[((unsigned)pk2 >> 1) + lane];
    unsigned int w3 = kvb[((unsigned)pk3 >> 1) + lane];
    edge_update(w0, pk0 & 1, qd, s0, s1, srun, acc);
    edge_update(w1, pk1 & 1, qd, s0, s1, srun, acc);
    edge_update(w2, pk2 & 1, qd, s0, s1, srun, acc);
    edge_update(w3, pk3 & 1, qd, s0, s1, srun, acc);
  }
  for (; j < cnt; ++j) {
    int pk = __builtin_amdgcn_readfirstlane(crow[j]);
    unsigned int wd = kvb[((unsigned)pk >> 1) + lane];
    edge_update(wd, pk & 1, qd, s0, s1, srun, acc);
  }
  hsg[(size_t)n * 64 + lane] = (srun > 0.f) ? (acc / srun) : 0.f;
}

// ---------------------------------------------------------------------------
// Output kernel over type-lists: Wa column in 64 VGPRs, one wave per node
// (4 nodes in flight per block), h row via s_loads, sigmoid-skip blend.
// ---------------------------------------------------------------------------
__global__ __launch_bounds__(256, 4) void out_kernel(
    const float* __restrict__ hsg, const float* __restrict__ x,
    const float* __restrict__ Wa, const float* __restrict__ skip,
    const int* __restrict__ tcnt, const int* __restrict__ tlist,
    float* __restrict__ out) {
  const int w = threadIdx.x >> 6;
  const int lane = threadIdx.x & 63;
  const int ty = blockIdx.y;

  const int cnt = __builtin_amdgcn_readfirstlane(tcnt[ty]);
  const int base = blockIdx.x * OCH;
  if (base >= cnt) return;
  const int iend = min(base + OCH, cnt);

  float wcol[64];
#pragma unroll
  for (int k = 0; k < 64; ++k)
    wcol[k] = Wa[(size_t)ty * 4096 + k * 64 + lane];

  const float alpha = 1.f / (1.f + __expf(-skip[ty]));
  const float beta = 1.f - alpha;
  const int* lst = tlist + ty * N_NODES;

  for (int i = base + w; i < iend; i += 4) {
    const int n = __builtin_amdgcn_readfirstlane(lst[i]);
    const float* hr = hsg + (size_t)n * 64;
    float a0 = 0.f, a1 = 0.f, a2 = 0.f, a3 = 0.f;
#pragma unroll
    for (int k = 0; k < 64; k += 4) {
      a0 = fmaf(hr[k + 0], wcol[k + 0], a0);
      a1 = fmaf(hr[k + 1], wcol[k + 1], a1);
      a2 = fmaf(hr[k + 2], wcol[k + 2], a2);
      a3 = fmaf(hr[k + 3], wcol[k + 3], a3);
    }
    size_t o = (size_t)n * 64 + lane;
    out[o] = ((a0 + a1) + (a2 + a3)) * alpha + x[o] * beta;
  }
}

// ---------------------------------------------------------------------------
extern "C" void kernel_launch(void* const* d_in, const int* in_sizes, int n_in,
                              void* d_out, int out_size, void* d_ws, size_t ws_size,
                              hipStream_t stream) {
  const float* x    = (const float*)d_in[0];
  const float* Wk   = (const float*)d_in[1];
  const float* Wq   = (const float*)d_in[2];
  const float* Wv   = (const float*)d_in[3];
  const float* Wa   = (const float*)d_in[4];
  const float* Ratt = (const float*)d_in[5];
  const float* Rmsg = (const float*)d_in[6];
  const float* pri  = (const float*)d_in[7];
  const float* skip = (const float*)d_in[8];
  const int* ntype  = (const int*)d_in[9];
  const int* etype  = (const int*)d_in[10];
  const int* src    = (const int*)d_in[11];
  const int* dst    = (const int*)d_in[12];
  float* out = (float*)d_out;

  // workspace layout
  float* q     = (float*)d_ws;                          // N*64 floats (also hsg)
  unsigned int* kvb = (unsigned int*)(q + (size_t)N_NODES * 64);  // ET*N*64 dwords
  int* rowstart = (int*)(kvb + (size_t)ET_TYPES * N_NODES * 64);  // N
  int* deg      = rowstart + N_NODES;                   // N
  int* tcnt     = deg + N_NODES;                        // 2
  int* cursor   = tcnt + 2;                             // N
  int* tlist    = cursor + N_NODES;                     // 2*N
  int* csr      = tlist + 2 * N_NODES;                  // E
  int* bsums    = csr + N_EDGES;                        // NB_SCAN (<=256)
  float* M      = (float*)(bsums + 256);                // NT*64*320 floats
  float* hsg    = q;                                    // alias (safe, see agg)

  prep_kernel<<<NB_SCAN, 256, 0, stream>>>(Wk, Wq, Wv, Ratt, Rmsg, M, deg, tcnt);

  build_kernel<<<(N_EDGES + 255) / 256, 256, 0, stream>>>(
      dst, ntype, deg, tcnt, tlist);

  dim3 pgrid((N_NODES + PCH - 1) / PCH, NT_TYPES);
  fused_proj_kernel<<<pgrid, 320, 0, stream>>>(x, M, tcnt, tlist, q, kvb);

  block_sums_kernel<<<NB_SCAN, 256, 0, stream>>>(deg, bsums);
  scan_sums_kernel<<<1, 256, 0, stream>>>(bsums);
  scan_final_kernel<<<NB_SCAN, 256, 0, stream>>>(deg, bsums, rowstart, cursor);
  fill_csr_kernel<<<(N_EDGES + 255) / 256, 256, 0, stream>>>(src, dst, etype, cursor, csr);

  aggregate_kernel<<<(N_NODES + 3) / 4, 256, 0, stream>>>(
      (const float*)q, (const unsigned int*)kvb, pri, rowstart, deg, csr, hsg);

  dim3 ogrid((N_NODES + OCH - 1) / OCH, NT_TYPES);
  out_kernel<<<ogrid, 256, 0, stream>>>(hsg, x, Wa, skip, tcnt, tlist, out);
}